// Round 15
// baseline (466.964 us; speedup 1.0000x reference)
//
#include <hip/hip_runtime.h>
#include <hip/hip_cooperative_groups.h>
#include <math.h>

namespace cg = cooperative_groups;

// Linear attention (elu+1 feature map), N=4, L=S=8192, H=8, D=Dv=64, fp32.
//
// out[n,l,h,:] = (qf[n,l,h,:] @ KV[n,h,:,:]) / (qf[n,l,h,:] . ksum[n,h,:] + eps)
// KV[n,h,d,dv] = sum_s kf[n,s,h,d] * vm[n,s,h,dv],  ksum = sum_s kf
//
// Split-bf16 MFMA everywhere (x = hi+lo; hh+lh+hl products, fp32 accum;
// dropped ll ~2^-18 rel). Denominators pure fp32.
// State (per pair, STATE=4160 words): KVT_hi bf16[64][64], KVT_lo bf16[64][64],
// ksum fp32[64].
//
// R15: SINGLE COOPERATIVE KERNEL (k1 -> grid.sync -> k2c -> grid.sync -> k3).
// Per-kernel levers are exhausted (8 structural k1 variants all ~equal; k3 at
// ~1.1x floor); the remaining identified cost is the 3-dispatch structure:
// launch ramps + full drains + partial-state HBM round-trip. 1024 blocks x
// 256 thr = exactly 4/CU (LDS 36.9KB, VGPR<=64 via launch_bounds). Fallback
// to the proven 3-kernel path if cooperative launch is rejected.

#define EPS 1e-6f

static constexpr int Nc = 4;
static constexpr int Lc = 8192;
static constexpr int Sc = 8192;
static constexpr int Hc = 8;
static constexpr int NH = Nc * Hc;         // 32
static constexpr int STATE = 64 * 64 + 64; // 4160 words per (n,h)
static constexpr int TS = 32;              // s-rows per staged tile in k1
static constexpr int TSP = 36;             // k1 bf16 LDS stride (72B rows)
static constexpr int QSP = 68;             // k3 bf16 LDS stride (fp32 out stride)
static constexpr int ARRB = 64 * TSP * 2;  // 4608 B per tile array
static constexpr int BUFB = 4 * ARRB;      // 18432 B per k1 buffer
static constexpr int SMEMB = 2 * BUFB;     // 36864 B flat LDS

typedef __attribute__((ext_vector_type(4))) short short4v;
typedef __attribute__((ext_vector_type(8))) short short8v;
typedef __attribute__((ext_vector_type(4))) float f32x4;

__device__ __forceinline__ float fmap(float x) {
    return x > 0.f ? x + 1.f : __expf(x);
}
__device__ __forceinline__ unsigned short f2bf(float x) {   // RNE float->bf16
    unsigned int u = __float_as_uint(x);
    u += 0x7FFFu + ((u >> 16) & 1u);
    return (unsigned short)(u >> 16);
}
__device__ __forceinline__ float bf2f(unsigned short h) {
    return __uint_as_float(((unsigned int)h) << 16);
}
__device__ __forceinline__ short8v ld8(const unsigned short* p) {
    short4v a = *(const short4v*)p;
    short4v b = *(const short4v*)(p + 4);
    return __builtin_shufflevector(a, b, 0, 1, 2, 3, 4, 5, 6, 7);
}
__device__ __forceinline__ unsigned int pack2(unsigned short a, unsigned short b) {
    return (unsigned)a | ((unsigned)b << 16);
}

struct K1Tile {
    float4 k0, k1, v0, v1;
    float m0, m1;
};

// ---------------------------------------------------------------------------
// k1 body: partial KV + ksum for (pair, chunk) = bid.  R14 verbatim.
// Double-buffered bf16 tiles in flat smem; one barrier per tile.
// ---------------------------------------------------------------------------
__device__ __forceinline__ void k1_body(
    int bid, const float* __restrict__ kg, const float* __restrict__ vg,
    const float* __restrict__ kv_mask, float* __restrict__ partial,
    int chunks, int sc, unsigned char* smem)
{
    const int pair = bid / chunks;
    const int chunk = bid - pair * chunks;
    const int n = pair >> 3;
    const int h = pair & 7;
    const int s0 = chunk * sc;
    const int t = threadIdx.x;
    const int g = t >> 4;
    const int c4 = (t & 15) * 4;
    const int lane = t & 63;
    const int wv = t >> 6;
    const int row16 = lane & 15;
    const int g8 = (lane >> 4) * 8;

    f32x4 acc[4] = {{0.f,0.f,0.f,0.f},{0.f,0.f,0.f,0.f},
                    {0.f,0.f,0.f,0.f},{0.f,0.f,0.f,0.f}};
    float ksm[4] = {0.f, 0.f, 0.f, 0.f};

    const size_t rowstride = (size_t)Hc * 64;
    const size_t gbase = ((size_t)n * Sc * Hc + h) * 64 + c4;
    const int mbase = n * Sc;

    auto issue = [&](int sbase, K1Tile& T) {
        const int s = s0 + sbase + 2 * g;
        const size_t be = gbase + (size_t)s * rowstride;
        T.k0 = *(const float4*)(kg + be);
        T.k1 = *(const float4*)(kg + be + rowstride);
        T.v0 = *(const float4*)(vg + be);
        T.v1 = *(const float4*)(vg + be + rowstride);
        T.m0 = kv_mask[mbase + s];
        T.m1 = kv_mask[mbase + s + 1];
    };

    auto process = [&](const K1Tile& T, int b) {
        unsigned char* base = smem + b * BUFB;
        const float* kep = &T.k0.x;
        const float* kop = &T.k1.x;
        const float* vep = &T.v0.x;
        const float* vop = &T.v1.x;
        #pragma unroll
        for (int j = 0; j < 4; ++j) {
            const int off = ((c4 + j) * TSP + 2 * g) * 2;
            const float fe = T.m0 * fmap(kep[j]);
            const float fo = T.m1 * fmap(kop[j]);
            ksm[j] += fe + fo;
            const unsigned short he = f2bf(fe), ho = f2bf(fo);
            *(unsigned int*)(base + 0 * ARRB + off) = pack2(he, ho);
            *(unsigned int*)(base + 1 * ARRB + off) =
                pack2(f2bf(fe - bf2f(he)), f2bf(fo - bf2f(ho)));
            const float ue = T.m0 * vep[j];
            const float uo = T.m1 * vop[j];
            const unsigned short vhe = f2bf(ue), vho = f2bf(uo);
            *(unsigned int*)(base + 2 * ARRB + off) = pack2(vhe, vho);
            *(unsigned int*)(base + 3 * ARRB + off) =
                pack2(f2bf(ue - bf2f(vhe)), f2bf(uo - bf2f(vho)));
        }
        __syncthreads();

        const unsigned short* kh = (const unsigned short*)(base + 0 * ARRB);
        const unsigned short* kl = (const unsigned short*)(base + 1 * ARRB);
        const unsigned short* vh = (const unsigned short*)(base + 2 * ARRB);
        const unsigned short* vl = (const unsigned short*)(base + 3 * ARRB);
        const int arow = (wv * 16 + row16) * TSP + g8;
        const short8v Ah = ld8(kh + arow);
        const short8v Al = ld8(kl + arow);
        #pragma unroll
        for (int bt = 0; bt < 4; ++bt) {
            const int brow = (bt * 16 + row16) * TSP + g8;
            const short8v Bh = ld8(vh + brow);
            const short8v Bl = ld8(vl + brow);
            acc[bt] = __builtin_amdgcn_mfma_f32_16x16x32_bf16(Ah, Bh, acc[bt], 0, 0, 0);
            acc[bt] = __builtin_amdgcn_mfma_f32_16x16x32_bf16(Al, Bh, acc[bt], 0, 0, 0);
            acc[bt] = __builtin_amdgcn_mfma_f32_16x16x32_bf16(Ah, Bl, acc[bt], 0, 0, 0);
        }
    };

    K1Tile A, B;
    issue(0, A);
    for (int sb = 0; sb < sc; sb += 2 * TS) {
        issue(sb + TS, B);
        process(A, 0);
        const int na = (sb + 2 * TS < sc) ? sb + 2 * TS : sb;
        issue(na, A);
        process(B, 1);
    }
    __syncthreads();

    float* outp = partial + (size_t)bid * STATE;
    float (*outs)[QSP] = reinterpret_cast<float (*)[QSP]>(smem);
    float* ksb = reinterpret_cast<float*>(smem + BUFB);
    #pragma unroll
    for (int bt = 0; bt < 4; ++bt) {
        #pragma unroll
        for (int r = 0; r < 4; ++r) {
            const int row = wv * 16 + (lane >> 4) * 4 + r;
            outs[row][bt * 16 + row16] = acc[bt][r];
        }
    }
    *(f32x4*)&ksb[g * 64 + c4] = (f32x4){ksm[0], ksm[1], ksm[2], ksm[3]};
    __syncthreads();

    #pragma unroll
    for (int p = 0; p < 4; ++p) {
        const int f = t + p * 256;
        const int row = f >> 4;
        const int cc = (f & 15) * 4;
        *(float4*)(outp + row * 64 + cc) = *(const float4*)&outs[row][cc];
    }
    if (t < 64) {
        float s = 0.f;
        #pragma unroll
        for (int i = 0; i < 16; ++i) s += ksb[i * 64 + t];
        outp[4096 + t] = s;
    }
    __syncthreads();   // smem reads done before caller reuses it
}

// ---------------------------------------------------------------------------
// k2c body: reduce nred partials -> transposed split-bf16 state for
// (pair, sub) = bid (bid < NH*2).  R14 verbatim.
// ---------------------------------------------------------------------------
__device__ __forceinline__ void k2c_body(
    int b, const float* __restrict__ src, float* __restrict__ dst, int nred)
{
    const int pair = b >> 1;
    const int sub = b & 1;
    const int t = threadIdx.x;
    const int ep = sub * 256 + t;
    const int d0 = (ep >> 4) * 2;
    const int c4 = (ep & 15) * 4;

    const float* sbase = src + (size_t)pair * nred * STATE;
    f32x4 a0 = {0.f,0.f,0.f,0.f}, a1 = {0.f,0.f,0.f,0.f};
    #pragma unroll 4
    for (int j = 0; j < nred; ++j) {
        const float* pj = sbase + (size_t)j * STATE;
        a0 += *(const f32x4*)(pj + (size_t)d0 * 64 + c4);
        a1 += *(const f32x4*)(pj + (size_t)(d0 + 1) * 64 + c4);
    }

    unsigned int* dw = (unsigned int*)(dst + (size_t)pair * STATE);
    #pragma unroll
    for (int i = 0; i < 4; ++i) {
        const int w = (c4 + i) * 32 + (d0 >> 1);
        const unsigned short h0 = f2bf(a0[i]), h1 = f2bf(a1[i]);
        dw[w] = pack2(h0, h1);
        dw[2048 + w] = pack2(f2bf(a0[i] - bf2f(h0)), f2bf(a1[i] - bf2f(h1)));
    }

    if (sub == 0 && t < 16) {
        f32x4 a = {0.f,0.f,0.f,0.f};
        #pragma unroll 4
        for (int j = 0; j < nred; ++j)
            a += *(const f32x4*)(sbase + (size_t)j * STATE + 4096 + t * 4);
        *(f32x4*)(dst + (size_t)pair * STATE + 4096 + t * 4) = a;
    }
}

// ---------------------------------------------------------------------------
// k3 body: FOUR 64x64 out tiles for (pair, quad) = bid (bid < NH*32).
// Flat-smem version of R14 k3: qsp0/qsp1/kvt0/kvt1 [64][QSP] u16 + ksum/dinv.
// Total 35328 B <= SMEMB.
// ---------------------------------------------------------------------------
__device__ __forceinline__ void k3_body(
    int bid, const float* __restrict__ qg, const float* __restrict__ state,
    const float* __restrict__ q_mask, float* __restrict__ outg,
    unsigned char* smem)
{
    unsigned short* qsp0 = (unsigned short*)smem;          // [64][QSP]
    unsigned short* qsp1 = qsp0 + 64 * QSP;
    unsigned short* kvt0 = qsp0 + 2 * 64 * QSP;
    unsigned short* kvt1 = qsp0 + 3 * 64 * QSP;
    float* ksum = (float*)(qsp0 + 4 * 64 * QSP);           // 64 floats
    float* dinv = ksum + 64;                               // 64 floats

    const int nblk = 32;
    const int pair = bid / nblk;
    const int lb = (bid - pair * nblk) * 4;
    const int n = pair >> 3;
    const int h = pair & 7;
    const int t = threadIdx.x;
    const int lane = t & 63;
    const int wv = t >> 6;
    const int row16 = lane & 15;
    const int g8 = (lane >> 4) * 8;

    const unsigned int* sw = (const unsigned int*)(state + (size_t)pair * STATE);
    #pragma unroll
    for (int i = 0; i < 8; ++i) {
        const int w = t + i * 256;
        const int dv = w >> 5;
        const int d2 = (w & 31) * 2;
        *(unsigned int*)&kvt0[dv * QSP + d2] = sw[w];
        *(unsigned int*)&kvt1[dv * QSP + d2] = sw[2048 + w];
    }
    if (t < 64) ksum[t] = ((const float*)state)[(size_t)pair * STATE + 4096 + t];
    __syncthreads();

    for (int tl = 0; tl < 4; ++tl) {
        const int l0 = (lb + tl) * 64;

        #pragma unroll
        for (int p = 0; p < 4; ++p) {
            const int f = t + p * 256;
            const int row = f >> 4;
            const int c4 = (f & 15) * 4;
            const int l = l0 + row;
            const size_t base = ((size_t)(n * Lc + l) * Hc + h) * 64 + c4;
            const float4 qq = *(const float4*)(qg + base);
            const float m = q_mask[n * Lc + l];
            const float q0 = m * fmap(qq.x), q1 = m * fmap(qq.y);
            const float q2 = m * fmap(qq.z), q3 = m * fmap(qq.w);
            const unsigned short h0 = f2bf(q0), h1 = f2bf(q1), h2 = f2bf(q2), h3 = f2bf(q3);
            *(unsigned int*)&qsp0[row * QSP + c4]     = pack2(h0, h1);
            *(unsigned int*)&qsp0[row * QSP + c4 + 2] = pack2(h2, h3);
            *(unsigned int*)&qsp1[row * QSP + c4]     = pack2(f2bf(q0 - bf2f(h0)), f2bf(q1 - bf2f(h1)));
            *(unsigned int*)&qsp1[row * QSP + c4 + 2] = pack2(f2bf(q2 - bf2f(h2)), f2bf(q3 - bf2f(h3)));
            float dp = q0 * ksum[c4] + q1 * ksum[c4 + 1] + q2 * ksum[c4 + 2] + q3 * ksum[c4 + 3];
            dp += __shfl_xor(dp, 1);
            dp += __shfl_xor(dp, 2);
            dp += __shfl_xor(dp, 4);
            dp += __shfl_xor(dp, 8);
            if ((t & 15) == 0) dinv[row] = 1.0f / (dp + EPS);
        }
        __syncthreads();

        f32x4 acc[4] = {{0.f,0.f,0.f,0.f},{0.f,0.f,0.f,0.f},
                        {0.f,0.f,0.f,0.f},{0.f,0.f,0.f,0.f}};
        #pragma unroll
        for (int ks = 0; ks < 2; ++ks) {
            const short8v Ah = ld8(&qsp0[(wv * 16 + row16) * QSP + ks * 32 + g8]);
            const short8v Al = ld8(&qsp1[(wv * 16 + row16) * QSP + ks * 32 + g8]);
            #pragma unroll
            for (int bt = 0; bt < 4; ++bt) {
                const short8v Bh = ld8(&kvt0[(bt * 16 + row16) * QSP + ks * 32 + g8]);
                const short8v Bl = ld8(&kvt1[(bt * 16 + row16) * QSP + ks * 32 + g8]);
                acc[bt] = __builtin_amdgcn_mfma_f32_16x16x32_bf16(Ah, Bh, acc[bt], 0, 0, 0);
                acc[bt] = __builtin_amdgcn_mfma_f32_16x16x32_bf16(Al, Bh, acc[bt], 0, 0, 0);
                acc[bt] = __builtin_amdgcn_mfma_f32_16x16x32_bf16(Ah, Bl, acc[bt], 0, 0, 0);
            }
        }
        __syncthreads();

        float (*outs)[QSP] = reinterpret_cast<float (*)[QSP]>(qsp0);
        #pragma unroll
        for (int bt = 0; bt < 4; ++bt) {
            #pragma unroll
            for (int r = 0; r < 4; ++r) {
                const int row = wv * 16 + (lane >> 4) * 4 + r;
                outs[row][bt * 16 + row16] = acc[bt][r] * dinv[row];
            }
        }
        __syncthreads();

        #pragma unroll
        for (int p = 0; p < 4; ++p) {
            const int f = t + p * 256;
            const int row = f >> 4;
            const int c4 = (f & 15) * 4;
            const size_t base = ((size_t)(n * Lc + l0 + row) * Hc + h) * 64 + c4;
            *(float4*)(outg + base) = *(const float4*)&outs[row][c4];
        }
        __syncthreads();
    }
}

// ---------------------------------------------------------------------------
// Fused cooperative kernel: k1 -> grid.sync -> k2c -> grid.sync -> k3.
// grid = NH*32 = 1024 blocks x 256 threads = 4 blocks/CU on 256 CUs.
// ---------------------------------------------------------------------------
__global__ __launch_bounds__(256, 4) void fused_all(
    const float* __restrict__ qg, const float* __restrict__ kg,
    const float* __restrict__ vg, const float* __restrict__ q_mask,
    const float* __restrict__ kv_mask, float* __restrict__ outg,
    float* __restrict__ fin, float* __restrict__ p1, int chunks)
{
    __shared__ __align__(16) unsigned char smem[SMEMB];
    cg::grid_group grid = cg::this_grid();
    const int bid = blockIdx.x;
    const int sc = Sc / chunks;

    if (bid < NH * chunks)
        k1_body(bid, kg, vg, kv_mask, p1, chunks, sc, smem);
    __threadfence();
    grid.sync();

    if (bid < NH * 2)
        k2c_body(bid, p1, fin, chunks);
    __threadfence();
    grid.sync();

    k3_body(bid, qg, fin, q_mask, outg, smem);
}

// ---------------------------------------------------------------------------
// Standalone fallback kernels (proven R14 path).
// ---------------------------------------------------------------------------
__global__ __launch_bounds__(256, 4) void k1_partial(
    const float* __restrict__ kg, const float* __restrict__ vg,
    const float* __restrict__ kv_mask,
    float* __restrict__ partial, int chunks, int sc)
{
    __shared__ __align__(16) unsigned char smem[SMEMB];
    k1_body(blockIdx.x, kg, vg, kv_mask, partial, chunks, sc, smem);
}

__global__ __launch_bounds__(256) void k2c_reduce_finalize(
    const float* __restrict__ src, float* __restrict__ dst, int nred)
{
    k2c_body(blockIdx.x, src, dst, nred);
}

__global__ __launch_bounds__(256, 4) void k3_out(
    const float* __restrict__ qg, const float* __restrict__ state,
    const float* __restrict__ q_mask, float* __restrict__ outg)
{
    __shared__ __align__(16) unsigned char smem[SMEMB];
    k3_body(blockIdx.x, qg, state, q_mask, outg, smem);
}

// ---------------------------------------------------------------------------
extern "C" void kernel_launch(void* const* d_in, const int* in_sizes, int n_in,
                              void* d_out, int out_size, void* d_ws, size_t ws_size,
                              hipStream_t stream)
{
    (void)in_sizes; (void)n_in; (void)out_size;
    const float* q       = (const float*)d_in[0];
    const float* k       = (const float*)d_in[1];
    const float* v       = (const float*)d_in[2];
    const float* q_mask  = (const float*)d_in[3];
    const float* kv_mask = (const float*)d_in[4];
    float* out = (float*)d_out;

    const size_t stBytes  = (size_t)STATE * sizeof(float);      // 16640
    const size_t finBytes = (size_t)NH * stBytes;               // 532480

    float* fin = (float*)d_ws;
    float* p1  = (float*)((char*)d_ws + finBytes);

    int chunks = 0;
    for (int c = 32; c >= 8; c >>= 1) {
        if (ws_size >= finBytes + (size_t)NH * c * stBytes) { chunks = c; break; }
    }

    bool done = false;
    if (chunks >= 8) {
        void* args[] = {(void*)&q, (void*)&k, (void*)&v, (void*)&q_mask,
                        (void*)&kv_mask, (void*)&out, (void*)&fin, (void*)&p1,
                        (void*)&chunks};
        hipError_t e = hipLaunchCooperativeKernel(
            (void*)fused_all, dim3(NH * 32), dim3(256), args, 0, stream);
        done = (e == hipSuccess);
    }

    if (!done) {
        if (chunks >= 8) {
            k1_partial<<<NH * chunks, 256, 0, stream>>>(k, v, kv_mask, p1, chunks, Sc / chunks);
            k2c_reduce_finalize<<<NH * 2, 256, 0, stream>>>(p1, fin, chunks);
        } else {
            k1_partial<<<NH, 256, 0, stream>>>(k, v, kv_mask, p1, 1, Sc);
            k2c_reduce_finalize<<<NH * 2, 256, 0, stream>>>(p1, fin, 1);
        }
        k3_out<<<NH * 32, 256, 0, stream>>>(q, fin, q_mask, out);
    }
}

// Round 16
// 74.226 us; speedup vs baseline: 6.2911x; 6.2911x over previous
//
#include <hip/hip_runtime.h>
#include <math.h>

// Linear attention (elu+1 feature map), N=4, L=S=8192, H=8, D=Dv=64, fp32.
//
// out[n,l,h,:] = (qf[n,l,h,:] @ KV[n,h,:,:]) / (qf[n,l,h,:] . ksum[n,h,:] + eps)
// KV[n,h,d,dv] = sum_s kf[n,s,h,d] * vm[n,s,h,dv],  ksum = sum_s kf
//
// Both GEMM phases use split-bf16 MFMA (x = hi + lo; three products hh+lh+hl,
// fp32 accumulate). Dropped ll term ~2^-18 relative. Denominators pure fp32.
// State format (per pair, STATE=4160 words): KVT_hi bf16[64][64] (2048 u32),
// KVT_lo bf16[64][64] (2048 u32), ksum fp32[64].
//
// R16 = R14 verbatim (measured optimum 74.60us). R15's cooperative fusion
// regressed 6.2x (grid.sync across 1024 blocks = global barrier convoy);
// the 3-launch structure is strictly better on this chip.

#define EPS 1e-6f

static constexpr int Nc = 4;
static constexpr int Lc = 8192;
static constexpr int Sc = 8192;
static constexpr int Hc = 8;
static constexpr int NH = Nc * Hc;         // 32
static constexpr int STATE = 64 * 64 + 64; // 4160 words per (n,h)
static constexpr int TS = 32;              // s-rows per staged tile in k1
static constexpr int TSP = 36;             // k1 bf16 LDS stride (72B rows)
static constexpr int QSP = 68;             // k3 bf16 LDS stride (also fp32 out stride)
static constexpr int ARRB = 64 * TSP * 2;  // 4608 B per tile array
static constexpr int BUFB = 4 * ARRB;      // 18432 B per buffer (kTh,kTl,vTh,vTl)

typedef __attribute__((ext_vector_type(4))) short short4v;
typedef __attribute__((ext_vector_type(8))) short short8v;
typedef __attribute__((ext_vector_type(4))) float f32x4;

__device__ __forceinline__ float fmap(float x) {
    return x > 0.f ? x + 1.f : __expf(x);
}
__device__ __forceinline__ unsigned short f2bf(float x) {   // RNE float->bf16
    unsigned int u = __float_as_uint(x);
    u += 0x7FFFu + ((u >> 16) & 1u);
    return (unsigned short)(u >> 16);
}
__device__ __forceinline__ float bf2f(unsigned short h) {
    return __uint_as_float(((unsigned int)h) << 16);
}
__device__ __forceinline__ short8v ld8(const unsigned short* p) {
    short4v a = *(const short4v*)p;
    short4v b = *(const short4v*)(p + 4);
    return __builtin_shufflevector(a, b, 0, 1, 2, 3, 4, 5, 6, 7);
}
__device__ __forceinline__ unsigned int pack2(unsigned short a, unsigned short b) {
    return (unsigned)a | ((unsigned)b << 16);
}

struct K1Tile {
    float4 k0, k1, v0, v1;
    float m0, m1;
};

// ---------------------------------------------------------------------------
// Kernel 1 (MFMA): partial KV + ksum per (pair, chunk).
// grid.x = NH * chunks, block = 256 (4 waves).  sc multiple of 64.
// Double-buffered bf16 tiles (36864 B flat LDS): buf0 @0, buf1 @18432, each
// {kTh,kTl,vTh,vTl}[64][TSP].  ONE __syncthreads per tile.
// Epilogue: outs fp32[64][QSP] aliases buf0, ksb fp32[16][64] aliases buf1.
// Output: fp32 KV[d][dv] + ksum at 4096 (reduced by k2c).
// ---------------------------------------------------------------------------
__global__ __launch_bounds__(256, 4) void k1_partial(
    const float* __restrict__ kg, const float* __restrict__ vg,
    const float* __restrict__ kv_mask,
    float* __restrict__ partial, int chunks, int sc)
{
    __shared__ __align__(16) unsigned char smem[2 * BUFB];

    const int bid = blockIdx.x;
    const int pair = bid / chunks;
    const int chunk = bid - pair * chunks;
    const int n = pair >> 3;
    const int h = pair & 7;
    const int s0 = chunk * sc;
    const int t = threadIdx.x;
    const int g = t >> 4;            // 0..15 (s-pair group)
    const int c4 = (t & 15) * 4;     // d/dv column base
    const int lane = t & 63;
    const int wv = t >> 6;           // wave id 0..3
    const int row16 = lane & 15;
    const int g8 = (lane >> 4) * 8;  // k-slice base within 32

    f32x4 acc[4] = {{0.f,0.f,0.f,0.f},{0.f,0.f,0.f,0.f},
                    {0.f,0.f,0.f,0.f},{0.f,0.f,0.f,0.f}};
    float ksm[4] = {0.f, 0.f, 0.f, 0.f};

    const size_t rowstride = (size_t)Hc * 64;                  // 512 floats per s
    const size_t gbase = ((size_t)n * Sc * Hc + h) * 64 + c4;
    const int mbase = n * Sc;

    auto issue = [&](int sbase, K1Tile& T) {
        const int s = s0 + sbase + 2 * g;
        const size_t be = gbase + (size_t)s * rowstride;
        T.k0 = *(const float4*)(kg + be);
        T.k1 = *(const float4*)(kg + be + rowstride);
        T.v0 = *(const float4*)(vg + be);
        T.v1 = *(const float4*)(vg + be + rowstride);
        T.m0 = kv_mask[mbase + s];
        T.m1 = kv_mask[mbase + s + 1];
    };

    // convert tile into buffer b, ONE barrier, MFMA from buffer b
    auto process = [&](const K1Tile& T, int b) {
        unsigned char* base = smem + b * BUFB;
        const float* kep = &T.k0.x;
        const float* kop = &T.k1.x;
        const float* vep = &T.v0.x;
        const float* vop = &T.v1.x;
        #pragma unroll
        for (int j = 0; j < 4; ++j) {
            const int off = ((c4 + j) * TSP + 2 * g) * 2;
            const float fe = T.m0 * fmap(kep[j]);
            const float fo = T.m1 * fmap(kop[j]);
            ksm[j] += fe + fo;
            const unsigned short he = f2bf(fe), ho = f2bf(fo);
            *(unsigned int*)(base + 0 * ARRB + off) = pack2(he, ho);
            *(unsigned int*)(base + 1 * ARRB + off) =
                pack2(f2bf(fe - bf2f(he)), f2bf(fo - bf2f(ho)));
            const float ue = T.m0 * vep[j];
            const float uo = T.m1 * vop[j];
            const unsigned short vhe = f2bf(ue), vho = f2bf(uo);
            *(unsigned int*)(base + 2 * ARRB + off) = pack2(vhe, vho);
            *(unsigned int*)(base + 3 * ARRB + off) =
                pack2(f2bf(ue - bf2f(vhe)), f2bf(uo - bf2f(vho)));
        }
        __syncthreads();   // tile visible; prior tile's reads already ordered
                           // before the previous barrier (alternating buffers)

        const unsigned short* kh = (const unsigned short*)(base + 0 * ARRB);
        const unsigned short* kl = (const unsigned short*)(base + 1 * ARRB);
        const unsigned short* vh = (const unsigned short*)(base + 2 * ARRB);
        const unsigned short* vl = (const unsigned short*)(base + 3 * ARRB);
        const int arow = (wv * 16 + row16) * TSP + g8;
        const short8v Ah = ld8(kh + arow);
        const short8v Al = ld8(kl + arow);
        #pragma unroll
        for (int bt = 0; bt < 4; ++bt) {
            const int brow = (bt * 16 + row16) * TSP + g8;
            const short8v Bh = ld8(vh + brow);
            const short8v Bl = ld8(vl + brow);
            acc[bt] = __builtin_amdgcn_mfma_f32_16x16x32_bf16(Ah, Bh, acc[bt], 0, 0, 0);
            acc[bt] = __builtin_amdgcn_mfma_f32_16x16x32_bf16(Al, Bh, acc[bt], 0, 0, 0);
            acc[bt] = __builtin_amdgcn_mfma_f32_16x16x32_bf16(Ah, Bl, acc[bt], 0, 0, 0);
        }
    };

    // ping-pong register sets + alternating LDS buffers
    K1Tile A, B;
    issue(0, A);
    for (int sb = 0; sb < sc; sb += 2 * TS) {
        issue(sb + TS, B);
        process(A, 0);
        const int na = (sb + 2 * TS < sc) ? sb + 2 * TS : sb;   // clamp at tail
        issue(na, A);
        process(B, 1);
    }
    __syncthreads();   // last MFMA reads done before aliasing buffers

    // ---- epilogue: stage partial KV in outs (aliases buf0), ksum in ksb
    // (aliases buf1); coalesced float4 stores.
    float* outp = partial + (size_t)bid * STATE;
    float (*outs)[QSP] = reinterpret_cast<float (*)[QSP]>(smem);
    float* ksb = reinterpret_cast<float*>(smem + BUFB);      // [16][64]
    #pragma unroll
    for (int bt = 0; bt < 4; ++bt) {
        #pragma unroll
        for (int r = 0; r < 4; ++r) {
            const int row = wv * 16 + (lane >> 4) * 4 + r;   // D: col=lane&15
            outs[row][bt * 16 + row16] = acc[bt][r];
        }
    }
    *(f32x4*)&ksb[g * 64 + c4] = (f32x4){ksm[0], ksm[1], ksm[2], ksm[3]};
    __syncthreads();

    #pragma unroll
    for (int p = 0; p < 4; ++p) {
        const int f = t + p * 256;          // float4 index over [64][16]
        const int row = f >> 4;
        const int cc = (f & 15) * 4;
        *(float4*)(outp + row * 64 + cc) = *(const float4*)&outs[row][cc];
    }
    if (t < 64) {
        float s = 0.f;
        #pragma unroll
        for (int i = 0; i < 16; ++i) s += ksb[i * 64 + t];
        outp[4096 + t] = s;
    }
}

// ---------------------------------------------------------------------------
// Kernel 2c: fused reduce + finalize.  grid = NH * 2 blocks of 256.
// Thread (sub*256+t) = ep in [0,512) owns KV rows d0=(ep>>4)*2, d0+1, cols
// c4..c4+3: reduces nred partials in fp32, then packs transposed split-bf16
// state words directly (w = dv*32 + d0/2, hi at w, lo at 2048+w).
// ---------------------------------------------------------------------------
__global__ __launch_bounds__(256) void k2c_reduce_finalize(
    const float* __restrict__ src, float* __restrict__ dst, int nred)
{
    const int b = blockIdx.x;
    const int pair = b >> 1;
    const int sub = b & 1;
    const int t = threadIdx.x;
    const int ep = sub * 256 + t;          // 0..511
    const int d0 = (ep >> 4) * 2;          // 0,2,..,62
    const int c4 = (ep & 15) * 4;

    const float* sbase = src + (size_t)pair * nred * STATE;
    f32x4 a0 = {0.f,0.f,0.f,0.f}, a1 = {0.f,0.f,0.f,0.f};
    #pragma unroll 4
    for (int j = 0; j < nred; ++j) {
        const float* pj = sbase + (size_t)j * STATE;
        a0 += *(const f32x4*)(pj + (size_t)d0 * 64 + c4);
        a1 += *(const f32x4*)(pj + (size_t)(d0 + 1) * 64 + c4);
    }

    unsigned int* dw = (unsigned int*)(dst + (size_t)pair * STATE);
    #pragma unroll
    for (int i = 0; i < 4; ++i) {
        const int w = (c4 + i) * 32 + (d0 >> 1);
        const unsigned short h0 = f2bf(a0[i]), h1 = f2bf(a1[i]);
        dw[w] = pack2(h0, h1);
        dw[2048 + w] = pack2(f2bf(a0[i] - bf2f(h0)), f2bf(a1[i] - bf2f(h1)));
    }

    if (sub == 0 && t < 16) {
        f32x4 a = {0.f,0.f,0.f,0.f};
        #pragma unroll 4
        for (int j = 0; j < nred; ++j)
            a += *(const f32x4*)(sbase + (size_t)j * STATE + 4096 + t * 4);
        *(f32x4*)(dst + (size_t)pair * STATE + 4096 + t * 4) = a;
    }
}

// ---------------------------------------------------------------------------
// Kernel 3 (MFMA): FOUR 64x64 out tiles per block for one (n,h).
// grid.x = NH * 32, block = 256 (4 waves).  State staged once per block.
// ---------------------------------------------------------------------------
__global__ __launch_bounds__(256, 4) void k3_out(
    const float* __restrict__ qg, const float* __restrict__ state,
    const float* __restrict__ q_mask, float* __restrict__ outg)
{
    __shared__ __align__(16) unsigned short qsp[2][64][QSP]; // q hi/lo; reused as fp32 out
    __shared__ unsigned short kvt[2][64][QSP];               // KVT hi/lo [dv][d]
    __shared__ float ksum[64];
    __shared__ float dinv[64];

    const int nblk = 32;                // tile-quads per pair
    const int bid = blockIdx.x;
    const int pair = bid / nblk;
    const int lb = (bid - pair * nblk) * 4;   // first of 4 l-tiles
    const int n = pair >> 3;
    const int h = pair & 7;
    const int t = threadIdx.x;
    const int lane = t & 63;
    const int wv = t >> 6;
    const int row16 = lane & 15;
    const int g8 = (lane >> 4) * 8;

    // ---- stage state once: KVT hi/lo into padded LDS + ksum
    const unsigned int* sw = (const unsigned int*)(state + (size_t)pair * STATE);
    #pragma unroll
    for (int i = 0; i < 8; ++i) {
        const int w = t + i * 256;          // 0..2047
        const int dv = w >> 5;
        const int d2 = (w & 31) * 2;
        *(unsigned int*)&kvt[0][dv][d2] = sw[w];
        *(unsigned int*)&kvt[1][dv][d2] = sw[2048 + w];
    }
    if (t < 64) ksum[t] = ((const float*)state)[(size_t)pair * STATE + 4096 + t];
    __syncthreads();

    for (int tl = 0; tl < 4; ++tl) {
        const int l0 = (lb + tl) * 64;

        // ---- stage q (fmap+mask, split bf16) + denominators (fp32)
        #pragma unroll
        for (int p = 0; p < 4; ++p) {
            const int f = t + p * 256;
            const int row = f >> 4;
            const int c4 = (f & 15) * 4;
            const int l = l0 + row;
            const size_t base = ((size_t)(n * Lc + l) * Hc + h) * 64 + c4;
            const float4 qq = *(const float4*)(qg + base);
            const float m = q_mask[n * Lc + l];
            const float q0 = m * fmap(qq.x), q1 = m * fmap(qq.y);
            const float q2 = m * fmap(qq.z), q3 = m * fmap(qq.w);
            const unsigned short h0 = f2bf(q0), h1 = f2bf(q1), h2 = f2bf(q2), h3 = f2bf(q3);
            *(unsigned int*)&qsp[0][row][c4]     = pack2(h0, h1);
            *(unsigned int*)&qsp[0][row][c4 + 2] = pack2(h2, h3);
            *(unsigned int*)&qsp[1][row][c4]     = pack2(f2bf(q0 - bf2f(h0)), f2bf(q1 - bf2f(h1)));
            *(unsigned int*)&qsp[1][row][c4 + 2] = pack2(f2bf(q2 - bf2f(h2)), f2bf(q3 - bf2f(h3)));
            float dp = q0 * ksum[c4] + q1 * ksum[c4 + 1] + q2 * ksum[c4 + 2] + q3 * ksum[c4 + 3];
            dp += __shfl_xor(dp, 1);
            dp += __shfl_xor(dp, 2);
            dp += __shfl_xor(dp, 4);
            dp += __shfl_xor(dp, 8);
            if ((t & 15) == 0) dinv[row] = 1.0f / (dp + EPS);
        }
        __syncthreads();

        // ---- MFMA: out[l][dv] = sum_d qf[l][d] * KVT[dv][d]
        f32x4 acc[4] = {{0.f,0.f,0.f,0.f},{0.f,0.f,0.f,0.f},
                        {0.f,0.f,0.f,0.f},{0.f,0.f,0.f,0.f}};
        #pragma unroll
        for (int ks = 0; ks < 2; ++ks) {
            const short8v Ah = ld8(&qsp[0][wv * 16 + row16][ks * 32 + g8]);
            const short8v Al = ld8(&qsp[1][wv * 16 + row16][ks * 32 + g8]);
            #pragma unroll
            for (int bt = 0; bt < 4; ++bt) {
                const short8v Bh = ld8(&kvt[0][bt * 16 + row16][ks * 32 + g8]);
                const short8v Bl = ld8(&kvt[1][bt * 16 + row16][ks * 32 + g8]);
                acc[bt] = __builtin_amdgcn_mfma_f32_16x16x32_bf16(Ah, Bh, acc[bt], 0, 0, 0);
                acc[bt] = __builtin_amdgcn_mfma_f32_16x16x32_bf16(Al, Bh, acc[bt], 0, 0, 0);
                acc[bt] = __builtin_amdgcn_mfma_f32_16x16x32_bf16(Ah, Bl, acc[bt], 0, 0, 0);
            }
        }
        __syncthreads();   // all A/B reads done; qsp may be reused

        // ---- scale + transpose through LDS (reuse qsp as fp32 [64][QSP])
        float (*outs)[QSP] = reinterpret_cast<float (*)[QSP]>(&qsp[0][0][0]);
        #pragma unroll
        for (int bt = 0; bt < 4; ++bt) {
            #pragma unroll
            for (int r = 0; r < 4; ++r) {
                const int row = wv * 16 + (lane >> 4) * 4 + r;
                outs[row][bt * 16 + row16] = acc[bt][r] * dinv[row];
            }
        }
        __syncthreads();

        // ---- coalesced float4 store
        #pragma unroll
        for (int p = 0; p < 4; ++p) {
            const int f = t + p * 256;
            const int row = f >> 4;
            const int c4 = (f & 15) * 4;
            const size_t base = ((size_t)(n * Lc + l0 + row) * Hc + h) * 64 + c4;
            *(float4*)(outg + base) = *(const float4*)&outs[row][c4];
        }
        __syncthreads();   // outs/dinv dead before next tile overwrites qsp
    }
}

// ---------------------------------------------------------------------------
extern "C" void kernel_launch(void* const* d_in, const int* in_sizes, int n_in,
                              void* d_out, int out_size, void* d_ws, size_t ws_size,
                              hipStream_t stream)
{
    (void)in_sizes; (void)n_in; (void)out_size;
    const float* q       = (const float*)d_in[0];
    const float* k       = (const float*)d_in[1];
    const float* v       = (const float*)d_in[2];
    const float* q_mask  = (const float*)d_in[3];
    const float* kv_mask = (const float*)d_in[4];
    float* out = (float*)d_out;

    const size_t stBytes  = (size_t)STATE * sizeof(float);      // 16640
    const size_t finBytes = (size_t)NH * stBytes;               // 532480

    float* fin = (float*)d_ws;
    float* p1  = (float*)((char*)d_ws + finBytes);

    int chunks = 0;
    for (int c = 32; c >= 8; c >>= 1) {
        if (ws_size >= finBytes + (size_t)NH * c * stBytes) { chunks = c; break; }
    }

    if (chunks >= 8) {
        k1_partial<<<NH * chunks, 256, 0, stream>>>(k, v, kv_mask, p1, chunks, Sc / chunks);
        k2c_reduce_finalize<<<NH * 2, 256, 0, stream>>>(p1, fin, chunks);
    } else {
        // tiny-workspace fallback: single chunk, then convert
        k1_partial<<<NH, 256, 0, stream>>>(k, v, kv_mask, p1, 1, Sc);
        k2c_reduce_finalize<<<NH * 2, 256, 0, stream>>>(p1, fin, 1);
    }

    k3_out<<<NH * 32, 256, 0, stream>>>(q, fin, q_mask, out);
}